// Round 16
// baseline (147.539 us; speedup 1.0000x reference)
//
#include <hip/hip_runtime.h>
#include <math.h>

#define KBINS 8192
#define DDIM  16384      // 2*K
#define HID   2048
#define LASTROW 16384    // the t row of W1 (row index D)

#define NRG1 1024        // mv1 row-groups (16 rows each); part1 depth = 1024
#define C2 8             // rows per mv2 chunk
#define NCH2 256         // 2048/8; grid (8,256) = 2048 blocks -> 8 blocks/CU

static constexpr float SQRT2_F  = 1.4142135623730951f;
static constexpr float INVSQ2PI = 0.3989422804014327f;   // 1/sqrt(2*pi)

// Branch-free erf approximation (A&S 7.1.26), |err| < 1.5e-7.
__device__ __forceinline__ float fast_erff(float x) {
    float ax = fabsf(x);
    float t  = 1.0f / fmaf(0.3275911f, ax, 1.0f);
    float p  = t * (0.254829592f +
               t * (-0.284496736f +
               t * (1.421413741f +
               t * (-1.453152027f +
               t * 1.061405429f))));
    float r = 1.0f - p * __expf(-ax * ax);
    return copysignf(r, x);
}

// ---- K1: mv1 partials. grid (2, 1024) = 2048 blocks, 8/CU.
// Block: 16 rows x 1024-col half; thread: 16 independent float4 loads (proven ILP).
// part1[rg][c]: depth 1024 (halved vs R10) -> 8 MB. ----
__global__ void __launch_bounds__(256)
mv1_partial(const float* __restrict__ mu, const float* __restrict__ W1,
            float* __restrict__ part1) {
    __shared__ float a_s[16];
    int rg = blockIdx.y;                      // 0..1023
    int r0 = rg * 16;
    if (threadIdx.x < 16) a_s[threadIdx.x] = mu[r0 + threadIdx.x];
    __syncthreads();
    int c0 = blockIdx.x * 1024 + threadIdx.x * 4;
    const float* wp = W1 + (size_t)r0 * HID + c0;
    float4 acc0 = {0.f, 0.f, 0.f, 0.f};
    float4 acc1 = {0.f, 0.f, 0.f, 0.f};
#pragma unroll
    for (int k = 0; k < 16; k += 2) {
        float a0 = a_s[k];
        float a1 = a_s[k + 1];
        const float4 w0 = *reinterpret_cast<const float4*>(wp + (size_t)k * HID);
        const float4 w1 = *reinterpret_cast<const float4*>(wp + (size_t)(k + 1) * HID);
        acc0.x += a0 * w0.x; acc0.y += a0 * w0.y; acc0.z += a0 * w0.z; acc0.w += a0 * w0.w;
        acc1.x += a1 * w1.x; acc1.y += a1 * w1.y; acc1.z += a1 * w1.z; acc1.w += a1 * w1.w;
    }
    float4 acc = {acc0.x + acc1.x, acc0.y + acc1.y, acc0.z + acc1.z, acc0.w + acc1.w};
    *reinterpret_cast<float4*>(part1 + (size_t)rg * HID + c0) = acc;
}

// ---- K2: h = leaky(b1 + t*W1[D] + 1024-deep col-sums of part1). grid 256. ----
__global__ void __launch_bounds__(256)
h_reduce(const float* __restrict__ part1, const float* __restrict__ b1,
         const float* __restrict__ W1, const float* __restrict__ t,
         float* __restrict__ h) {
    __shared__ float red[32][9];
    int col_l = threadIdx.x & 7;
    int sub   = threadIdx.x >> 3;             // 0..31
    int c0    = blockIdx.x * 8;
    float s = 0.f;
    const float* p = part1 + c0 + col_l;
#pragma unroll 8
    for (int m = 0; m < 32; ++m)
        s += p[(size_t)(sub + (m << 5)) * HID];
    red[sub][col_l] = s;
    __syncthreads();
    if (threadIdx.x < 8) {
        int c = c0 + threadIdx.x;
        float v = b1[c] + t[0] * W1[(size_t)LASTROW * HID + c];
#pragma unroll
        for (int q = 0; q < 32; ++q) v += red[q][threadIdx.x];
        h[c] = (v >= 0.f) ? v : 0.01f * v;
    }
}

// ---- K3: mv2 partials. grid (8, 256) = 2048 blocks, 8/CU. R10's exact shape. ----
__global__ void __launch_bounds__(256)
mv2_partial(const float* __restrict__ h, const float* __restrict__ W2,
            float* __restrict__ part2) {
    __shared__ float hs[C2];
    int r0    = blockIdx.y * C2;
    int cbase = blockIdx.x * 2048;
    if (threadIdx.x < C2) hs[threadIdx.x] = h[r0 + threadIdx.x];
    __syncthreads();
    int c0 = cbase + threadIdx.x * 4;
    const float* wp = W2 + (size_t)r0 * DDIM;
    float4 acc0 = {0.f, 0.f, 0.f, 0.f};
    float4 acc1 = {0.f, 0.f, 0.f, 0.f};
#pragma unroll
    for (int k = 0; k < C2; ++k) {
        float a = hs[k];
        const float4 w0 = *reinterpret_cast<const float4*>(wp + (size_t)k * DDIM + c0);
        const float4 w1 = *reinterpret_cast<const float4*>(wp + (size_t)k * DDIM + c0 + 1024);
        acc0.x += a * w0.x; acc0.y += a * w0.y; acc0.z += a * w0.z; acc0.w += a * w0.w;
        acc1.x += a * w1.x; acc1.y += a * w1.y; acc1.z += a * w1.z; acc1.w += a * w1.w;
    }
    float* pp = part2 + (size_t)blockIdx.y * DDIM;
    *reinterpret_cast<float4*>(pp + c0)        = acc0;
    *reinterpret_cast<float4*>(pp + c0 + 1024) = acc1;
}

// ---- K4: fused scalars + cdf. grid 2048 blocks x 4 rows, 8/CU.
// Prologue: 256-deep column sums of part2 (8 cols) + per-row scalars.
// Main: proven 99.5%-of-peak midpoint-rule write loop. ----
__global__ void __launch_bounds__(256)
cdf_fused(const float* __restrict__ part2, const float* __restrict__ b2,
          const float* __restrict__ mu, const float* __restrict__ t,
          const float* __restrict__ gamma, float* __restrict__ out) {
    __shared__ float red[32][8];
    __shared__ float sv[8];
    __shared__ float sA[4], sB[4], sCf[4], sEr[4];
    const int tid = threadIdx.x;
    const int i0  = blockIdx.x * 4;
    {
        int col = tid & 7;                    // 0-3: mu_eps cols, 4-7: ln_sig cols
        int sub = tid >> 3;                   // 0..31
        int gc  = (col < 4) ? (i0 + col) : (KBINS + i0 + col - 4);
        float s = 0.f;
        const float* p = part2 + gc;
#pragma unroll
        for (int m = 0; m < 8; ++m)
            s += p[(size_t)(sub + (m << 5)) * DDIM];
        red[sub][col] = s;
    }
    __syncthreads();
    if (tid < 8) {
        int gc = (tid < 4) ? (i0 + tid) : (KBINS + i0 + tid - 4);
        float v = b2[gc];
#pragma unroll
        for (int q = 0; q < 32; ++q) v += red[q][tid];
        sv[tid] = v;
    }
    __syncthreads();
    if (tid < 4) {
        float s0 = sv[tid];
        float s1 = sv[tid + 4];
        float g  = gamma[0];
        float pe = 1.0f / (1.0f - g);
        float pm = g - pe;
        bool use_nn = (t[0] >= 1e-10f);
        float mval = use_nn ? powf(mu[i0 + tid], pm) * powf(s0, pe) : 0.0f;
        float invs = use_nn ? powf(1.0f - g, 0.5f) * expf(-0.5f * s1) : 1.0f;
        const float sc = 2.0f / 8191.0f;
        float A = sc * invs;
        sA[tid]  = A;
        sB[tid]  = (-1.0f / 8191.0f - mval) * invs;
        sCf[tid] = INVSQ2PI * A;
        float z = (8190.0f / 8191.0f - mval) * invs * (1.0f / SQRT2_F);
        sEr[tid] = 0.5f * (1.0f - fast_erff(z));
    }
    __syncthreads();
    for (int rr = 0; rr < 4; ++rr) {
        float A    = sA[rr];
        float B    = sB[rr];
        float coef = sCf[rr];
        float er   = sEr[rr];
        float* orow = out + (size_t)(i0 + rr) * KBINS;
#pragma unroll
        for (int it = 0; it < 8; ++it) {
            int j0 = it * 1024 + tid * 4;
            float4 r;
            if (j0 < 4096) {
                float u0 = fmaf((float)j0, A, B);
                float u1 = u0 + A;
                float u2 = u1 + A;
                float u3 = u2 + A;
                r.x = coef * __expf(-0.5f * u0 * u0);
                r.y = coef * __expf(-0.5f * u1 * u1);
                r.z = coef * __expf(-0.5f * u2 * u2);
                r.w = coef * __expf(-0.5f * u3 * u3);
            } else if (j0 == 4096) {
                r.x = er;
                r.y = r.z = r.w = 0.f;
            } else {
                r.x = r.y = r.z = r.w = 0.f;
            }
            *reinterpret_cast<float4*>(orow + j0) = r;
        }
    }
}

extern "C" void kernel_launch(void* const* d_in, const int* in_sizes, int n_in,
                              void* d_out, int out_size, void* d_ws, size_t ws_size,
                              hipStream_t stream) {
    const float* mu    = (const float*)d_in[0];
    const float* t     = (const float*)d_in[1];
    const float* gamma = (const float*)d_in[2];
    const float* W1    = (const float*)d_in[3];
    const float* b1    = (const float*)d_in[4];
    const float* W2    = (const float*)d_in[5];
    const float* b2    = (const float*)d_in[6];
    float* out = (float*)d_out;

    float* ws    = (float*)d_ws;
    float* part1 = ws;                               // 1024*2048 = 8 MB
    float* h     = part1 + (size_t)NRG1 * HID;       // 2048
    float* part2 = h + HID;                          // 256*16384 = 16 MB

    mv1_partial<<<dim3(2, NRG1),  dim3(256), 0, stream>>>(mu, W1, part1);
    h_reduce   <<<dim3(256),      dim3(256), 0, stream>>>(part1, b1, W1, t, h);
    mv2_partial<<<dim3(8, NCH2),  dim3(256), 0, stream>>>(h, W2, part2);
    cdf_fused  <<<dim3(2048),     dim3(256), 0, stream>>>(part2, b2, mu, t, gamma, out);
}